// Round 1
// baseline (656.789 us; speedup 1.0000x reference)
//
#include <hip/hip_runtime.h>
#include <hip/hip_bf16.h>
#include <stdint.h>

#define BB 64
#define NN 1024
#define MM 1024
#define P0_CHUNKS 16   // blocks per batch in convert+colpart pass (64 rows each)
#define CP_CHUNKS 16   // blocks per batch in col pass (2 row-groups each -> 32 partials)

typedef unsigned short u16;
typedef __attribute__((ext_vector_type(8))) unsigned short ushort8v;

__device__ __forceinline__ float bf2f(u16 h) {
    union { uint32_t u; float f; } c; c.u = ((uint32_t)h) << 16; return c.f;
}
__device__ __forceinline__ u16 f2bf(float f) {
    union { float f; uint32_t u; } c; c.f = f;
    return (u16)((c.u + 0x7FFFu + ((c.u >> 16) & 1u)) >> 16);  // RNE
}

// Pass 0: read f32 s, write bf16 copy of s/temp, and accumulate per-column
// online (max, sumexp) partials for the initial axis-1 logsumexp (u == 0).
__global__ __launch_bounds__(256) void k_convert_colpart(
    const float* __restrict__ s, const float* __restrict__ temp,
    u16* __restrict__ sbf, float2* __restrict__ part)
{
    const int b     = blockIdx.x / P0_CHUNKS;
    const int chunk = blockIdx.x % P0_CHUNKS;
    const int col0  = threadIdx.x * 4;            // 256 thr * 4 cols = 1024
    const float invt = 1.0f / temp[0];
    const int rows = NN / P0_CHUNKS;              // 64
    const size_t base = ((size_t)b * NN + (size_t)chunk * rows) * MM + col0;
    const float* sp = s + base;
    u16* op = sbf + base;
    float m0=-INFINITY, m1=-INFINITY, m2=-INFINITY, m3=-INFINITY;
    float S0=0.f, S1=0.f, S2=0.f, S3=0.f;
    for (int r = 0; r < rows; ++r) {
        float4 x = *reinterpret_cast<const float4*>(sp + (size_t)r * MM);
        float a0 = x.x * invt, a1 = x.y * invt, a2 = x.z * invt, a3 = x.w * invt;
        ushort4 o; o.x=f2bf(a0); o.y=f2bf(a1); o.z=f2bf(a2); o.w=f2bf(a3);
        *reinterpret_cast<ushort4*>(op + (size_t)r * MM) = o;
        float n;
        n=fmaxf(m0,a0); S0=S0*__expf(m0-n)+__expf(a0-n); m0=n;
        n=fmaxf(m1,a1); S1=S1*__expf(m1-n)+__expf(a1-n); m1=n;
        n=fmaxf(m2,a2); S2=S2*__expf(m2-n)+__expf(a2-n); m2=n;
        n=fmaxf(m3,a3); S3=S3*__expf(m3-n)+__expf(a3-n); m3=n;
    }
    float2* pp = part + ((size_t)b * P0_CHUNKS + chunk) * MM + col0;
    pp[0]=make_float2(m0,S0); pp[1]=make_float2(m1,S1);
    pp[2]=make_float2(m2,S2); pp[3]=make_float2(m3,S3);
}

// Combine nparts (m,S) partials per column -> v[b,j] = logsumexp
__global__ __launch_bounds__(256) void k_combine(
    const float2* __restrict__ part, float* __restrict__ vout, int nparts)
{
    const int idx = blockIdx.x * 256 + threadIdx.x;   // 0..BB*MM-1
    const int b = idx >> 10;
    const int j = idx & (MM - 1);
    float m = -INFINITY, S = 0.0f;
    for (int p = 0; p < nparts; ++p) {
        float2 pr = part[((size_t)b * nparts + p) * MM + j];
        float n = fmaxf(m, pr.x);
        S = S * __expf(m - n) + pr.y * __expf(pr.x - n);
        m = n;
    }
    vout[idx] = m + __logf(S);
}

// Row pass: u[b,i] = lse_j( sbf[b,i,:] - v[b,:] ).  One wave per row.
__global__ __launch_bounds__(256) void k_row_lse(
    const u16* __restrict__ sbf, const float* __restrict__ v, float* __restrict__ u)
{
    const int lane = threadIdx.x & 63;
    const int row  = blockIdx.x * 4 + (threadIdx.x >> 6);   // b*NN + i
    const int b    = row >> 10;
    const u16*   rp = sbf + (size_t)row * MM + lane * 16;
    const float* vp = v + (size_t)b * MM + lane * 16;
    ushort8v h0 = *reinterpret_cast<const ushort8v*>(rp);
    ushort8v h1 = *reinterpret_cast<const ushort8v*>(rp + 8);
    float vv[16];
    *reinterpret_cast<float4*>(&vv[0])  = *reinterpret_cast<const float4*>(vp);
    *reinterpret_cast<float4*>(&vv[4])  = *reinterpret_cast<const float4*>(vp + 4);
    *reinterpret_cast<float4*>(&vv[8])  = *reinterpret_cast<const float4*>(vp + 8);
    *reinterpret_cast<float4*>(&vv[12]) = *reinterpret_cast<const float4*>(vp + 12);
    float x[16];
#pragma unroll
    for (int k = 0; k < 8; ++k) x[k] = bf2f(h0[k]) - vv[k];
#pragma unroll
    for (int k = 0; k < 8; ++k) x[8 + k] = bf2f(h1[k]) - vv[8 + k];
    float m = x[0];
#pragma unroll
    for (int k = 1; k < 16; ++k) m = fmaxf(m, x[k]);
#pragma unroll
    for (int off = 32; off >= 1; off >>= 1) m = fmaxf(m, __shfl_xor(m, off));
    float S = 0.f;
#pragma unroll
    for (int k = 0; k < 16; ++k) S += __expf(x[k] - m);
#pragma unroll
    for (int off = 32; off >= 1; off >>= 1) S += __shfl_xor(S, off);
    if (lane == 0) u[row] = m + __logf(S);
}

// Col pass partials: per-column online (m,S) of ( sbf[b,:,j] - u[b,:] )
__global__ __launch_bounds__(256) void k_col_part(
    const u16* __restrict__ sbf, const float* __restrict__ u, float2* __restrict__ part)
{
    const int b     = blockIdx.x / CP_CHUNKS;
    const int chunk = blockIdx.x % CP_CHUNKS;
    const int c = threadIdx.x & 127;      // 128 col-octets cover 1024 cols
    const int g = threadIdx.x >> 7;       // 2 row groups
    const int col0 = c * 8;
    const int rows = NN / CP_CHUNKS;      // 64 rows per chunk
    const int row0 = chunk * rows + g;
    const u16*   sp = sbf + ((size_t)b * NN + row0) * MM + col0;
    const float* up = u + (size_t)b * NN + row0;
    float m[8], S[8];
#pragma unroll
    for (int k = 0; k < 8; ++k) { m[k] = -INFINITY; S[k] = 0.f; }
    for (int r = 0; r < rows / 2; ++r) {            // rows row0 + 2r
        ushort8v h = *reinterpret_cast<const ushort8v*>(sp + (size_t)(2 * r) * MM);
        float uu = up[2 * r];
#pragma unroll
        for (int k = 0; k < 8; ++k) {
            float xx = bf2f(h[k]) - uu;
            float n = fmaxf(m[k], xx);
            S[k] = S[k] * __expf(m[k] - n) + __expf(xx - n);
            m[k] = n;
        }
    }
    float2* pp = part + ((size_t)b * (2 * CP_CHUNKS) + chunk * 2 + g) * MM + col0;
#pragma unroll
    for (int k = 0; k < 8; ++k) pp[k] = make_float2(m[k], S[k]);
}

// Final fused pass: out = exp( s/temp - v - lse_j(s/temp - v) ), from f32 source.
__global__ __launch_bounds__(256) void k_final(
    const float* __restrict__ s, const float* __restrict__ temp,
    const float* __restrict__ v, float* __restrict__ out)
{
    const int lane = threadIdx.x & 63;
    const int row  = blockIdx.x * 4 + (threadIdx.x >> 6);
    const int b    = row >> 10;
    const float invt = 1.0f / temp[0];
    const float* sp = s + (size_t)row * MM + lane * 16;
    const float* vp = v + (size_t)b * MM + lane * 16;
    float x[16];
#pragma unroll
    for (int q = 0; q < 4; ++q) {
        float4 xs = *reinterpret_cast<const float4*>(sp + q * 4);
        float4 vs = *reinterpret_cast<const float4*>(vp + q * 4);
        x[4*q+0] = xs.x * invt - vs.x;
        x[4*q+1] = xs.y * invt - vs.y;
        x[4*q+2] = xs.z * invt - vs.z;
        x[4*q+3] = xs.w * invt - vs.w;
    }
    float m = x[0];
#pragma unroll
    for (int k = 1; k < 16; ++k) m = fmaxf(m, x[k]);
#pragma unroll
    for (int off = 32; off >= 1; off >>= 1) m = fmaxf(m, __shfl_xor(m, off));
    float S = 0.f;
#pragma unroll
    for (int k = 0; k < 16; ++k) S += __expf(x[k] - m);
#pragma unroll
    for (int off = 32; off >= 1; off >>= 1) S += __shfl_xor(S, off);
    const float L = m + __logf(S);
    float* op = out + (size_t)row * MM + lane * 16;
#pragma unroll
    for (int q = 0; q < 4; ++q) {
        float4 o;
        o.x = __expf(x[4*q+0] - L);
        o.y = __expf(x[4*q+1] - L);
        o.z = __expf(x[4*q+2] - L);
        o.w = __expf(x[4*q+3] - L);
        *reinterpret_cast<float4*>(op + q * 4) = o;
    }
}

extern "C" void kernel_launch(void* const* d_in, const int* in_sizes, int n_in,
                              void* d_out, int out_size, void* d_ws, size_t ws_size,
                              hipStream_t stream) {
    (void)in_sizes; (void)n_in; (void)out_size; (void)ws_size;
    const float* s    = (const float*)d_in[0];
    const float* temp = (const float*)d_in[1];
    float* out = (float*)d_out;

    // Scratch layout:
    //   sbf  : bf16 copy of s/temp, in d_out[0 .. 128MB)   (dead before k_final writes)
    //   part : column partials,      in d_out[128MB .. 144MB)
    //   u, v : potentials in d_ws (512 KB) -- must be outside d_out (k_final reads v
    //          while overwriting all of d_out).
    u16*    sbf  = (u16*)d_out;
    float2* part = (float2*)((char*)d_out + ((size_t)BB * NN * MM) * sizeof(u16));
    float*  u    = (float*)d_ws;
    float*  v    = u + (size_t)BB * NN;

    dim3 blk(256);
    // initial axis-1 (column) normalization, fused with f32->bf16 convert
    k_convert_colpart<<<dim3(BB * P0_CHUNKS), blk, 0, stream>>>(s, temp, sbf, part);
    k_combine<<<dim3(BB * MM / 256), blk, 0, stream>>>(part, v, P0_CHUNKS);
    // iterations i=0..13 (i=14 fused into k_final)
    for (int i = 0; i < 14; ++i) {
        if ((i & 1) == 0) {
            // axis 2: u = lse_j(sbf - v)
            k_row_lse<<<dim3(BB * NN / 4), blk, 0, stream>>>(sbf, v, u);
        } else {
            // axis 1: v = lse_i(sbf - u)
            k_col_part<<<dim3(BB * CP_CHUNKS), blk, 0, stream>>>(sbf, u, part);
            k_combine<<<dim3(BB * MM / 256), blk, 0, stream>>>(part, v, 2 * CP_CHUNKS);
        }
    }
    // i=14 (axis 2) + exp, from full-precision source
    k_final<<<dim3(BB * NN / 4), blk, 0, stream>>>(s, temp, v, out);
}

// Round 2
// 387.314 us; speedup vs baseline: 1.6958x; 1.6958x over previous
//
#include <hip/hip_runtime.h>
#include <stdint.h>

#define BB 64
#define NN 1024
#define MM 1024
#define CH 16           // row-chunks per batch: blocks/batch in sweep kernels

typedef unsigned short u16;
typedef __attribute__((ext_vector_type(8))) unsigned short ushort8v;

__device__ __forceinline__ float bf2f(u16 h) {
    union { uint32_t u; float f; } c; c.u = ((uint32_t)h) << 16; return c.f;
}
__device__ __forceinline__ u16 f2bf(float f) {
    union { float f; uint32_t u; } c; c.f = f;
    return (u16)((c.u + 0x7FFFu + ((c.u >> 16) & 1u)) >> 16);  // RNE
}

// Pass 0: read f32 s, write bf16 copy of s/temp, accumulate per-column
// plain sum-exp partials for the initial axis-1 logsumexp (u == 0).
// Safe without max: |s/temp| <~ 6 -> exp <= 403, sum over 64 rows <= 26K.
__global__ __launch_bounds__(256) void k_convert(
    const float* __restrict__ s, const float* __restrict__ temp,
    u16* __restrict__ sbf, float* __restrict__ part)
{
    const int b     = blockIdx.x / CH;
    const int chunk = blockIdx.x % CH;
    const int col0  = threadIdx.x * 4;
    const float invt = 1.0f / temp[0];
    const int rows = NN / CH;                          // 64
    const size_t base = ((size_t)b * NN + (size_t)chunk * rows) * MM + col0;
    const float* sp = s + base;
    u16* op = sbf + base;
    float S0 = 0.f, S1 = 0.f, S2 = 0.f, S3 = 0.f;
    for (int r = 0; r < rows; ++r) {
        float4 x = *reinterpret_cast<const float4*>(sp + (size_t)r * MM);
        float a0 = x.x * invt, a1 = x.y * invt, a2 = x.z * invt, a3 = x.w * invt;
        ushort4 o; o.x = f2bf(a0); o.y = f2bf(a1); o.z = f2bf(a2); o.w = f2bf(a3);
        *reinterpret_cast<ushort4*>(op + (size_t)r * MM) = o;
        S0 += __expf(a0); S1 += __expf(a1); S2 += __expf(a2); S3 += __expf(a3);
    }
    *reinterpret_cast<float4*>(part + ((size_t)b * CH + chunk) * MM + col0) =
        make_float4(S0, S1, S2, S3);
}

// Combine CH partial column sums -> v[b,j] = log(sum)
__global__ __launch_bounds__(256) void k_combine(
    const float* __restrict__ part, float* __restrict__ vout)
{
    const int idx = blockIdx.x * 256 + threadIdx.x;    // 0..BB*MM-1
    const int b = idx >> 10;
    const int j = idx & (MM - 1);
    float S = 0.f;
#pragma unroll
    for (int p = 0; p < CH; ++p) S += part[((size_t)b * CH + p) * MM + j];
    vout[idx] = __logf(S);
}

// Fused sweep: one pass over sbf performs BOTH the row update
//   u_i = log sum_j exp(sbf_ij - v_j)
// and the column-partial accumulation for the next col update
//   Scol_j += exp(sbf_ij - u_i) = t_j * exp(v_j) / Srow,  t_j = exp(sbf_ij - v_j)
// (one exp per element total; u never touches memory).
__global__ __launch_bounds__(256) void k_sweep(
    const u16* __restrict__ sbf, const float* __restrict__ v,
    float* __restrict__ part)
{
    __shared__ float sh[4][MM];                        // 16 KB
    const int b     = blockIdx.x / CH;
    const int chunk = blockIdx.x % CH;
    const int lane  = threadIdx.x & 63;
    const int wv    = threadIdx.x >> 6;                // 4 waves, 16 rows each
    const float* vp = v + (size_t)b * MM + lane * 16;
    float vv[16], ev[16];
    *reinterpret_cast<float4*>(&vv[0])  = *reinterpret_cast<const float4*>(vp);
    *reinterpret_cast<float4*>(&vv[4])  = *reinterpret_cast<const float4*>(vp + 4);
    *reinterpret_cast<float4*>(&vv[8])  = *reinterpret_cast<const float4*>(vp + 8);
    *reinterpret_cast<float4*>(&vv[12]) = *reinterpret_cast<const float4*>(vp + 12);
#pragma unroll
    for (int k = 0; k < 16; ++k) ev[k] = __expf(vv[k]);
    float Sc[16];
#pragma unroll
    for (int k = 0; k < 16; ++k) Sc[k] = 0.f;

    const int row0 = chunk * (NN / CH) + wv * 16;
    const u16* rp = sbf + ((size_t)b * NN + row0) * MM + lane * 16;
#pragma unroll 2
    for (int t = 0; t < 16; ++t) {
        ushort8v h0 = *reinterpret_cast<const ushort8v*>(rp + (size_t)t * MM);
        ushort8v h1 = *reinterpret_cast<const ushort8v*>(rp + (size_t)t * MM + 8);
        float te[16];
#pragma unroll
        for (int k = 0; k < 8; ++k) te[k]     = __expf(bf2f(h0[k]) - vv[k]);
#pragma unroll
        for (int k = 0; k < 8; ++k) te[8 + k] = __expf(bf2f(h1[k]) - vv[8 + k]);
        float Sr = 0.f;
#pragma unroll
        for (int k = 0; k < 16; ++k) Sr += te[k];
#pragma unroll
        for (int off = 32; off >= 1; off >>= 1) Sr += __shfl_xor(Sr, off);
        const float w = __builtin_amdgcn_rcpf(Sr);     // 1/Srow (~1 ulp)
#pragma unroll
        for (int k = 0; k < 16; ++k) Sc[k] = fmaf(te[k], ev[k] * w, Sc[k]);
    }
    // cross-wave reduce in LDS, then write one partial row per block
#pragma unroll
    for (int q = 0; q < 4; ++q)
        *reinterpret_cast<float4*>(&sh[wv][lane * 16 + q * 4]) =
            *reinterpret_cast<float4*>(&Sc[q * 4]);
    __syncthreads();
    const int c0 = threadIdx.x * 4;
    float4 a0 = *reinterpret_cast<float4*>(&sh[0][c0]);
    float4 a1 = *reinterpret_cast<float4*>(&sh[1][c0]);
    float4 a2 = *reinterpret_cast<float4*>(&sh[2][c0]);
    float4 a3 = *reinterpret_cast<float4*>(&sh[3][c0]);
    float4 r;
    r.x = (a0.x + a1.x) + (a2.x + a3.x);
    r.y = (a0.y + a1.y) + (a2.y + a3.y);
    r.z = (a0.z + a1.z) + (a2.z + a3.z);
    r.w = (a0.w + a1.w) + (a2.w + a3.w);
    *reinterpret_cast<float4*>(part + ((size_t)b * CH + chunk) * MM + c0) = r;
}

// Final fused pass: out = exp(x) / sum_j exp(x),  x = s/temp - v, from f32 source.
__global__ __launch_bounds__(256) void k_final(
    const float* __restrict__ s, const float* __restrict__ temp,
    const float* __restrict__ v, float* __restrict__ out)
{
    const int lane = threadIdx.x & 63;
    const int row  = blockIdx.x * 4 + (threadIdx.x >> 6);
    const int b    = row >> 10;
    const float invt = 1.0f / temp[0];
    const float* sp = s + (size_t)row * MM + lane * 16;
    const float* vp = v + (size_t)b * MM + lane * 16;
    float e[16];
    float S = 0.f;
#pragma unroll
    for (int q = 0; q < 4; ++q) {
        float4 xs = *reinterpret_cast<const float4*>(sp + q * 4);
        float4 vs = *reinterpret_cast<const float4*>(vp + q * 4);
        e[4*q+0] = __expf(xs.x * invt - vs.x);
        e[4*q+1] = __expf(xs.y * invt - vs.y);
        e[4*q+2] = __expf(xs.z * invt - vs.z);
        e[4*q+3] = __expf(xs.w * invt - vs.w);
        S += (e[4*q+0] + e[4*q+1]) + (e[4*q+2] + e[4*q+3]);
    }
#pragma unroll
    for (int off = 32; off >= 1; off >>= 1) S += __shfl_xor(S, off);
    const float w = 1.0f / S;
    float* op = out + (size_t)row * MM + lane * 16;
#pragma unroll
    for (int q = 0; q < 4; ++q) {
        float4 o;
        o.x = e[4*q+0] * w; o.y = e[4*q+1] * w;
        o.z = e[4*q+2] * w; o.w = e[4*q+3] * w;
        *reinterpret_cast<float4*>(op + q * 4) = o;
    }
}

extern "C" void kernel_launch(void* const* d_in, const int* in_sizes, int n_in,
                              void* d_out, int out_size, void* d_ws, size_t ws_size,
                              hipStream_t stream) {
    (void)in_sizes; (void)n_in; (void)out_size; (void)ws_size;
    const float* s    = (const float*)d_in[0];
    const float* temp = (const float*)d_in[1];
    float* out = (float*)d_out;

    // Scratch layout:
    //   sbf  : bf16 copy of s/temp, d_out[0 .. 128MB)   (dead before k_final writes)
    //   part : column partials (4MB), d_out[128MB .. 132MB)
    //   v    : potentials in d_ws (k_final reads v while overwriting d_out)
    u16*   sbf  = (u16*)d_out;
    float* part = (float*)((char*)d_out + ((size_t)BB * NN * MM) * sizeof(u16));
    float* v    = (float*)d_ws;

    dim3 blk(256);
    // initial axis-1 (column) normalization fused with f32->bf16 convert
    k_convert<<<dim3(BB * CH), blk, 0, stream>>>(s, temp, sbf, part);
    k_combine<<<dim3(BB * MM / 256), blk, 0, stream>>>(part, v);
    // iterations i=0..13: each fused sweep = row update (in-register) + col partials
    for (int p = 0; p < 7; ++p) {
        k_sweep<<<dim3(BB * CH), blk, 0, stream>>>(sbf, v, part);
        k_combine<<<dim3(BB * MM / 256), blk, 0, stream>>>(part, v);
    }
    // i=14 (axis 2 row norm) + exp, from full-precision source
    k_final<<<dim3(BB * NN / 4), blk, 0, stream>>>(s, temp, v, out);
}